// Round 11
// baseline (124.941 us; speedup 1.0000x reference)
//
#include <hip/hip_runtime.h>
#include <hip/hip_bf16.h>
#include <stdint.h>

// Problem constants (from reference)
#define C_   8
#define EPC_ 4
#define E_   32
#define K_   8
#define S_   256
#define H_   2048
#define M_   2048
#define ML_  8
#define CAP_ 256               // M / C
#define SK_  2048              // S*K
#define NROWS_ (E_ * M_)       // 65536 slot rows (r = e*M + dst)
#define BUF_ELEMS_ ((size_t)E_ * M_ * H_)   // 134217728
#define ZROWS_PER_BLOCK_ 8
#define NZERO_   (NROWS_ / ZROWS_PER_BLOCK_) // 8192 zero blocks
#define NGATHER_ (C_ * S_)                   // 2048 gather blocks

typedef float f32x4 __attribute__((ext_vector_type(4)));

// ---------------------------------------------------------------------------
// Kernel 1: wave-parallel stable rank. One wave per (chip, expert): 256 waves.
// For pick (c,i) with indices[c,i]==e, rank = #earlier matches (ballot+popc).
// Emits dstmap[c*SK+i] = slot row r = e*M + base + rank (or -1 if OOB drop),
// and cnt[c*E+e] = total matches. Every pick is written exactly once (expert
// ids always in [0,E)), so dstmap needs no init pass.
// ---------------------------------------------------------------------------
__global__ __launch_bounds__(64) void rank_kernel(
        const int* __restrict__ indices,
        const int* __restrict__ expert_offsets,
        int* __restrict__ dstmap,
        int* __restrict__ cnt) {
    const int c    = blockIdx.x >> 5;
    const int e    = blockIdx.x & 31;
    const int lane = threadIdx.x;
    const int* __restrict__ ip = indices + c * SK_;
    const int base = expert_offsets[c * E_ + e];

    int running = 0;
    const unsigned long long below = (lane == 63) ? (~0ULL >> 1)
                                                  : (1ULL << lane) - 1ULL;
    #pragma unroll 4
    for (int ch = 0; ch < SK_ / 64; ++ch) {
        const int i = ch * 64 + lane;
        const bool hit = (ip[i] == e);
        const unsigned long long m = __ballot(hit);
        if (hit) {
            const int dst = base + running + __popcll(m & below);
            dstmap[c * SK_ + i] =
                ((unsigned)dst < (unsigned)M_) ? (e * M_ + dst) : -1;
        }
        running += __popcll(m);
    }
    if (lane == 0) cnt[c * E_ + e] = running;
}

// ---------------------------------------------------------------------------
// Kernel 2 (fused, ZERO-FIRST) — R6 structure, single isolated change:
// gather-role stores are PLAIN (not NT). Mechanism: NT scattered 8 KB
// bursts bypass L2 and pay DRAM page-activates per burst (~4.3 TB/s
// effective); plain scattered stores land in L2 where adjacent occupied
// rows from different blocks merge and write back as longer contiguous
// spans (L2 = cross-block write-combining buffer). Gather x loads stay NT
// (bypass L2 -> no capacity conflict with the write-combining).
//  - blocks [0, NZERO): zero role, 8 consecutive slot rows (64 KB) each,
//    plain sequential stores (unchanged from R6). Occupied slots are a
//    dense prefix of each (e,chip) 256-slot region.
//  - blocks [NZERO, NZERO+NGATHER): gather role, one per (chip, token);
//    reads the x row ONCE (NT), stores to all K destination rows (plain);
//    threads 0..7 write the K meta rows (float-encoded ints — the harness
//    reads d_out as one f32 array).
// ---------------------------------------------------------------------------
__global__ __launch_bounds__(256) void fill_all(
        const float* __restrict__ x,
        const float* __restrict__ w,
        const int* __restrict__ dstmap,
        const int* __restrict__ cnt,
        float* __restrict__ buf,
        float* __restrict__ meta) {
    const int t = threadIdx.x;

    if (blockIdx.x < NZERO_) {
        // ----- zero role (byte-identical to R6) -----
        const int r0    = blockIdx.x * ZROWS_PER_BLOCK_;
        const int e     = r0 >> 11;
        const int dst0  = r0 & (M_ - 1);
        const int c     = dst0 >> 8;
        const int slot0 = dst0 & (CAP_ - 1);

        int nocc = cnt[c * E_ + e] - slot0;      // rows j < nocc are occupied
        if (nocc >= ZROWS_PER_BLOCK_) return;    // whole block occupied
        if (nocc < 0) nocc = 0;

        const f32x4 z = {0.f, 0.f, 0.f, 0.f};
        for (int j = nocc; j < ZROWS_PER_BLOCK_; ++j) {
            f32x4* __restrict__ brow =
                reinterpret_cast<f32x4*>(buf + (size_t)(r0 + j) * H_);
            brow[t]       = z;
            brow[t + 256] = z;
        }
        if (t >= nocc && t < ZROWS_PER_BLOCK_) {
            f32x4* __restrict__ mrow =
                reinterpret_cast<f32x4*>(meta + (size_t)(r0 + t) * ML_);
            const f32x4 m = {-1.f, -1.f, -1.f, -1.f};
            mrow[0] = m;
            mrow[1] = m;
        }
    } else {
        // ----- gather role (R6 layout; stores NT -> PLAIN) -----
        const int b     = blockIdx.x - NZERO_;   // c*S + token
        const int c     = b >> 8;
        const int token = b & (S_ - 1);

        const f32x4* __restrict__ src =
            reinterpret_cast<const f32x4*>(x + (size_t)b * H_);
        const f32x4 a0 = __builtin_nontemporal_load(src + t);
        const f32x4 a1 = __builtin_nontemporal_load(src + t + 256);

        const int* __restrict__ dm = dstmap + c * SK_ + token * K_;
        int d[K_];
        #pragma unroll
        for (int k = 0; k < K_; ++k) d[k] = dm[k];   // uniform across block

        #pragma unroll
        for (int k = 0; k < K_; ++k) {
            if (d[k] >= 0) {
                f32x4* __restrict__ brow =
                    reinterpret_cast<f32x4*>(buf + (size_t)d[k] * H_);
                brow[t]       = a0;
                brow[t + 256] = a1;
            }
        }

        if (t < K_) {
            const int k  = t;
            const int dd = d[k];
            if (dd >= 0) {
                const int e = dd >> 11;              // dd = e*M + dst
                // wbits: f32 -> bf16 (RNE) -> int16 -> sign-extend int32
                const float wv    = w[b * K_ + k];
                const uint32_t u  = __float_as_uint(wv);
                const uint32_t rb = (u + 0x7FFFu + ((u >> 16) & 1u)) >> 16;
                const int wb      = (int)(short)(unsigned short)rb;
                f32x4* __restrict__ mrow =
                    reinterpret_cast<f32x4*>(meta + (size_t)dd * ML_);
                mrow[0] = (f32x4){(float)c, (float)token, (float)k, (float)e};
                mrow[1] = (f32x4){(float)wb, 0.f, 0.f, 0.f};
            }
        }
    }
}

// ---------------------------------------------------------------------------
extern "C" void kernel_launch(void* const* d_in, const int* in_sizes, int n_in,
                              void* d_out, int out_size, void* d_ws, size_t ws_size,
                              hipStream_t stream) {
    const float* x   = (const float*)d_in[0];   // (C,S,H) f32
    const float* w   = (const float*)d_in[1];   // (C,S,K) f32
    const int* idx   = (const int*)d_in[2];     // (C,S,K) i32
    const int* eo    = (const int*)d_in[3];     // (C,E)   i32

    float* buf  = (float*)d_out;                 // (1,C,EPC,M,H) f32
    float* meta = buf + BUF_ELEMS_;              // (1,C,EPC,M,ML), float-encoded

    int* dstmap = (int*)d_ws;                    // C*SK int32 = 64 KiB
    int* cnt    = dstmap + C_ * SK_;             // C*E int32  = 1 KiB

    // 1: stable ranks -> per-pick destination rows + per-(c,e) counts
    rank_kernel<<<C_ * E_, 64, 0, stream>>>(idx, eo, dstmap, cnt);
    // 2: fused fill, zero blocks first, gather blocks trail (plain stores)
    fill_all<<<NZERO_ + NGATHER_, 256, 0, stream>>>(x, w, dstmap, cnt, buf, meta);
}

// Round 12
// 104.557 us; speedup vs baseline: 1.1950x; 1.1950x over previous
//
#include <hip/hip_runtime.h>
#include <hip/hip_bf16.h>
#include <stdint.h>

// Problem constants (from reference)
#define C_   8
#define EPC_ 4
#define E_   32
#define K_   8
#define S_   256
#define H_   2048
#define M_   2048
#define ML_  8
#define CAP_ 256               // M / C
#define SK_  2048              // S*K
#define NROWS_ (E_ * M_)       // 65536 slot rows (r = e*M + dst)
#define BUF_ELEMS_ ((size_t)E_ * M_ * H_)   // 134217728
#define ZROWS_PER_BLOCK_ 8
#define NZERO_   (NROWS_ / ZROWS_PER_BLOCK_) // 8192 zero blocks
#define NGATHER_ (C_ * S_)                   // 2048 gather blocks

typedef float f32x4 __attribute__((ext_vector_type(4)));

// ---------------------------------------------------------------------------
// FINAL (revert to R6, the measured best: 104.6 us).
// Store-mode matrix measured across rounds: sequential NT==plain (R5/R6),
// scattered NT >> plain (R11: plain +20us — L2 allocation churn). Dest-
// ordered restructurings all lost (R7/R9/R10): the data-dependent slot
// permutation belongs on the WRITE side (fire-and-forget NT), never the
// read side (latency-poisoned dependent loads under a write flood).
// ---------------------------------------------------------------------------

// ---------------------------------------------------------------------------
// Kernel 1: wave-parallel stable rank. One wave per (chip, expert): 256 waves.
// For pick (c,i) with indices[c,i]==e, rank = #earlier matches (ballot+popc).
// Emits dstmap[c*SK+i] = slot row r = e*M + base + rank (or -1 if OOB drop),
// and cnt[c*E+e] = total matches. Every pick is written exactly once (expert
// ids always in [0,E)), so dstmap needs no init pass.
// ---------------------------------------------------------------------------
__global__ __launch_bounds__(64) void rank_kernel(
        const int* __restrict__ indices,
        const int* __restrict__ expert_offsets,
        int* __restrict__ dstmap,
        int* __restrict__ cnt) {
    const int c    = blockIdx.x >> 5;
    const int e    = blockIdx.x & 31;
    const int lane = threadIdx.x;
    const int* __restrict__ ip = indices + c * SK_;
    const int base = expert_offsets[c * E_ + e];

    int running = 0;
    const unsigned long long below = (lane == 63) ? (~0ULL >> 1)
                                                  : (1ULL << lane) - 1ULL;
    #pragma unroll 4
    for (int ch = 0; ch < SK_ / 64; ++ch) {
        const int i = ch * 64 + lane;
        const bool hit = (ip[i] == e);
        const unsigned long long m = __ballot(hit);
        if (hit) {
            const int dst = base + running + __popcll(m & below);
            dstmap[c * SK_ + i] =
                ((unsigned)dst < (unsigned)M_) ? (e * M_ + dst) : -1;
        }
        running += __popcll(m);
    }
    if (lane == 0) cnt[c * E_ + e] = running;
}

// ---------------------------------------------------------------------------
// Kernel 2 (fused, ZERO-FIRST): one dispatch, two block roles.
//  - blocks [0, NZERO): zero role, 8 consecutive slot rows (64 KB) each.
//    Occupied slots are a dense prefix of each (e,chip) 256-slot region
//    (expert_offsets[c,e] = c*CAP), so one cnt load decides all 8 rows.
//  - blocks [NZERO, NZERO+NGATHER): gather role, one per (chip, token).
//    Reads the x row ONCE (NT loads — no reuse, keep L2 for writes), streams
//    it to all K destination rows (NT stores — scattered, no L2 allocation);
//    threads 0..7 write the K meta rows.
// Zero-first ordering: the 403 MB sequential zero stream runs pure; gather
// blocks only start as the zero blocks drain, so stream mixing is confined
// to the dispatch tail. No inter-dispatch drain.
// Meta values are FLOAT-encoded ints (harness reads d_out as one f32 array).
// ---------------------------------------------------------------------------
__global__ __launch_bounds__(256) void fill_all(
        const float* __restrict__ x,
        const float* __restrict__ w,
        const int* __restrict__ dstmap,
        const int* __restrict__ cnt,
        float* __restrict__ buf,
        float* __restrict__ meta) {
    const int t = threadIdx.x;

    if (blockIdx.x < NZERO_) {
        // ----- zero role -----
        const int r0    = blockIdx.x * ZROWS_PER_BLOCK_;
        const int e     = r0 >> 11;
        const int dst0  = r0 & (M_ - 1);
        const int c     = dst0 >> 8;
        const int slot0 = dst0 & (CAP_ - 1);

        int nocc = cnt[c * E_ + e] - slot0;      // rows j < nocc are occupied
        if (nocc >= ZROWS_PER_BLOCK_) return;    // whole block occupied
        if (nocc < 0) nocc = 0;

        const f32x4 z = {0.f, 0.f, 0.f, 0.f};
        for (int j = nocc; j < ZROWS_PER_BLOCK_; ++j) {
            f32x4* __restrict__ brow =
                reinterpret_cast<f32x4*>(buf + (size_t)(r0 + j) * H_);
            brow[t]       = z;
            brow[t + 256] = z;
        }
        if (t >= nocc && t < ZROWS_PER_BLOCK_) {
            f32x4* __restrict__ mrow =
                reinterpret_cast<f32x4*>(meta + (size_t)(r0 + t) * ML_);
            const f32x4 m = {-1.f, -1.f, -1.f, -1.f};
            mrow[0] = m;
            mrow[1] = m;
        }
    } else {
        // ----- gather role -----
        const int b     = blockIdx.x - NZERO_;   // c*S + token
        const int c     = b >> 8;
        const int token = b & (S_ - 1);

        const f32x4* __restrict__ src =
            reinterpret_cast<const f32x4*>(x + (size_t)b * H_);
        const f32x4 a0 = __builtin_nontemporal_load(src + t);
        const f32x4 a1 = __builtin_nontemporal_load(src + t + 256);

        const int* __restrict__ dm = dstmap + c * SK_ + token * K_;
        int d[K_];
        #pragma unroll
        for (int k = 0; k < K_; ++k) d[k] = dm[k];   // uniform across block

        #pragma unroll
        for (int k = 0; k < K_; ++k) {
            if (d[k] >= 0) {
                f32x4* __restrict__ brow =
                    reinterpret_cast<f32x4*>(buf + (size_t)d[k] * H_);
                __builtin_nontemporal_store(a0, brow + t);
                __builtin_nontemporal_store(a1, brow + t + 256);
            }
        }

        if (t < K_) {
            const int k  = t;
            const int dd = d[k];
            if (dd >= 0) {
                const int e = dd >> 11;              // dd = e*M + dst
                // wbits: f32 -> bf16 (RNE) -> int16 -> sign-extend int32
                const float wv    = w[b * K_ + k];
                const uint32_t u  = __float_as_uint(wv);
                const uint32_t rb = (u + 0x7FFFu + ((u >> 16) & 1u)) >> 16;
                const int wb      = (int)(short)(unsigned short)rb;
                f32x4* __restrict__ mrow =
                    reinterpret_cast<f32x4*>(meta + (size_t)dd * ML_);
                const f32x4 m0 = {(float)c, (float)token, (float)k, (float)e};
                const f32x4 m1 = {(float)wb, 0.f, 0.f, 0.f};
                __builtin_nontemporal_store(m0, mrow);
                __builtin_nontemporal_store(m1, mrow + 1);
            }
        }
    }
}

// ---------------------------------------------------------------------------
extern "C" void kernel_launch(void* const* d_in, const int* in_sizes, int n_in,
                              void* d_out, int out_size, void* d_ws, size_t ws_size,
                              hipStream_t stream) {
    const float* x   = (const float*)d_in[0];   // (C,S,H) f32
    const float* w   = (const float*)d_in[1];   // (C,S,K) f32
    const int* idx   = (const int*)d_in[2];     // (C,S,K) i32
    const int* eo    = (const int*)d_in[3];     // (C,E)   i32

    float* buf  = (float*)d_out;                 // (1,C,EPC,M,H) f32
    float* meta = buf + BUF_ELEMS_;              // (1,C,EPC,M,ML), float-encoded

    int* dstmap = (int*)d_ws;                    // C*SK int32 = 64 KiB
    int* cnt    = dstmap + C_ * SK_;             // C*E int32  = 1 KiB

    // 1: stable ranks -> per-pick destination rows + per-(c,e) counts
    rank_kernel<<<C_ * E_, 64, 0, stream>>>(idx, eo, dstmap, cnt);
    // 2: fused fill, zero blocks first, gather blocks trail
    fill_all<<<NZERO_ + NGATHER_, 256, 0, stream>>>(x, w, dstmap, cnt, buf, meta);
}